// Round 6
// baseline (389.319 us; speedup 1.0000x reference)
//
#include <hip/hip_runtime.h>
#include <math.h>

#define N 4096
#define B 16
#define NN (N * N)
#define R 2                    // rows per block (grid = 2048 -> 32 waves/CU)
#define MAX_SYN 100
#define MIN_SYN 10
#define CREATE_T 0.3f
#define PRUNE_T 0.01f
#define INIT_STRENGTH 0.01f
#define EPS 1e-10f
#define QSCALE 181.0f          // 127 levels over (0.3, ~1.0]
#define MCAP 128               // boundary-level mini-list cap
#define NSLOT 64

typedef float f32x4 __attribute__((ext_vector_type(4)));

// ---------------- kernel 1: per-column normalization + acc zeroing ----------------
// norm layout [B][N]; 64 blocks x 64 threads
__global__ void prep_kernel(const float* __restrict__ act,
                            float* __restrict__ norm,
                            float* __restrict__ acc) {
    const int tid = threadIdx.x;
    if (blockIdx.x == 0) {
        for (int k = tid; k < NSLOT * 4; k += 64) acc[k] = 0.f;
    }
    int j = blockIdx.x * 64 + tid;
    float a[B];
    float sum = 0.f;
#pragma unroll
    for (int b = 0; b < B; ++b) { a[b] = act[b * N + j]; sum += a[b]; }
    float mean = sum * (1.0f / B);
    float var = 0.f;
#pragma unroll
    for (int b = 0; b < B; ++b) { float c = a[b] - mean; var += c * c; }
    var *= (1.0f / (B - 1));   // ddof=1
    float sd = sqrtf(var);
    if (sd < 1e-8f) sd = 1e-8f;
    float inv = 1.0f / sd;
#pragma unroll
    for (int b = 0; b < B; ++b) norm[b * N + j] = (a[b] - mean) * inv;
}

// ---------------- kernel 2: fused corr + select + prune ----------------
// enc code: 0 = nothing; else bit7 = sign(corr), bits0-6 = level+1 (level 0..126)
__global__ __launch_bounds__(256, 8) void fused_kernel(const float* __restrict__ W,
                                                       const float* __restrict__ norm,
                                                       float* __restrict__ out,
                                                       float* __restrict__ acc) {
    __shared__ unsigned char enc[R][N];            // 8 KB
    __shared__ int hist[128];
    __shared__ int cred[4][2 * R];
    __shared__ int sred[2];
    __shared__ int ctl[2];
    __shared__ int mlist[MCAP];
    __shared__ int mcount;

    const int tid = threadIdx.x;
    const int lane = tid & 63;
    const int wid = tid >> 6;
    const int row0 = blockIdx.x * R;

    // wave-uniform row vectors (scalar loads)
    float srow[R][B];
#pragma unroll
    for (int r = 0; r < R; ++r)
#pragma unroll
        for (int b = 0; b < B; ++b) srow[r][b] = norm[b * N + row0 + r];

    // ---------- pass A: corr + counts + encode ----------
    int cnt_nz[R], cnt_cand[R], cnt_str[R];
#pragma unroll
    for (int r = 0; r < R; ++r) { cnt_nz[r] = 0; cnt_cand[r] = 0; cnt_str[r] = 0; }

#pragma unroll
    for (int g = 0; g < 4; ++g) {
        const int j0 = g * 1024 + tid * 4;
        f32x4 w4[R];
#pragma unroll
        for (int r = 0; r < R; ++r)
            w4[r] = *(const f32x4*)(W + (size_t)(row0 + r) * N + j0);   // regular cached load
        float cc[R][4];
#pragma unroll
        for (int r = 0; r < R; ++r) { cc[r][0] = 0.f; cc[r][1] = 0.f; cc[r][2] = 0.f; cc[r][3] = 0.f; }
#pragma unroll
        for (int half = 0; half < 2; ++half) {     // 8 batch rows of norm in flight
            f32x4 nb[8];
#pragma unroll
            for (int b = 0; b < 8; ++b)
                nb[b] = *(const f32x4*)(norm + (half * 8 + b) * N + j0);
#pragma unroll
            for (int r = 0; r < R; ++r) {
#pragma unroll
                for (int b = 0; b < 8; ++b) {
                    float s = srow[r][half * 8 + b];
                    cc[r][0] = fmaf(s, nb[b][0], cc[r][0]);
                    cc[r][1] = fmaf(s, nb[b][1], cc[r][1]);
                    cc[r][2] = fmaf(s, nb[b][2], cc[r][2]);
                    cc[r][3] = fmaf(s, nb[b][3], cc[r][3]);
                }
            }
        }
#pragma unroll
        for (int r = 0; r < R; ++r) {
            unsigned pack = 0;
#pragma unroll
            for (int i = 0; i < 4; ++i) {
                float c = cc[r][i] * 0.0625f;
                float aw = fabsf(w4[r][i]);
                float ac = fabsf(c);
                cnt_nz[r] += (aw > EPS) ? 1 : 0;
                cnt_str[r] += (aw >= PRUNE_T) ? 1 : 0;
                if ((ac > CREATE_T) && (aw < EPS)) {
                    cnt_cand[r] += 1;
                    int lvl = (int)((ac - CREATE_T) * QSCALE);
                    if (lvl > 126) lvl = 126;
                    unsigned code = (unsigned)(lvl + 1) | ((c < 0.f) ? 0x80u : 0u);
                    pack |= code << (8 * i);
                }
            }
            *(unsigned*)&enc[r][j0] = pack;
        }
    }

    // ---------- reduce 2R packed counters ----------
    int vals[2 * R];
#pragma unroll
    for (int r = 0; r < R; ++r) {
        vals[r] = cnt_nz[r] | (cnt_str[r] << 16);
        vals[R + r] = cnt_cand[r];
    }
#pragma unroll
    for (int v = 0; v < 2 * R; ++v) {
        int x = vals[v];
#pragma unroll
        for (int off = 32; off > 0; off >>= 1) x += __shfl_down(x, off, 64);
        if (lane == 0) cred[wid][v] = x;
    }
    __syncthreads();
    int tot[2 * R];
#pragma unroll
    for (int v = 0; v < 2 * R; ++v) tot[v] = cred[0][v] + cred[1][v] + cred[2][v] + cred[3][v];

    int nr[R];
    int canp_bits = 0;
    int created_total = 0;
#pragma unroll
    for (int r = 0; r < R; ++r) {
        int cur = tot[r] & 0xFFFF;
        int str = tot[r] >> 16;
        int C = tot[R + r];
        int n = 0;
        if (cur < MAX_SYN) { int room = MAX_SYN - cur; n = C < room ? C : room; }
        nr[r] = n;
        created_total += n;
        if ((str + n) > MIN_SYN) canp_bits |= (1 << r);   // strong(w1) = strong(W) + created
    }

    // ---------- per-row top-n selection on 7-bit levels ----------
#pragma unroll
    for (int r = 0; r < R; ++r) {
        const int n = nr[r];
        const int C = tot[R + r];
        if (n >= C) continue;           // all candidates created (uniform branch)
        if (n == 0) {                   // none created: clear row codes
#pragma unroll
            for (int g = 0; g < 4; ++g)
                *(unsigned*)&enc[r][g * 1024 + tid * 4] = 0u;
            continue;
        }
        __syncthreads();                // protect hist/mlist/ctl from previous row
        if (tid < 128) hist[tid] = 0;
        if (tid == 0) mcount = 0;
        __syncthreads();
        unsigned cw[4];
#pragma unroll
        for (int g = 0; g < 4; ++g) {
            cw[g] = *(unsigned*)&enc[r][g * 1024 + tid * 4];
#pragma unroll
            for (int i = 0; i < 4; ++i) {
                unsigned code = (cw[g] >> (8 * i)) & 0xFFu;
                if (code) atomicAdd(&hist[(code & 0x7Fu) - 1], 1);
            }
        }
        __syncthreads();
        // suffix sum over 127 bins (two waves, shfl)
        int h = 0, v = 0;
        if (tid < 128) {
            h = hist[tid];
            v = h;
#pragma unroll
            for (int off = 1; off < 64; off <<= 1) {
                int t = __shfl_down(v, off, 64);
                v += (lane + off < 64) ? t : 0;
            }
            if (lane == 0) sred[wid] = v;
        }
        __syncthreads();
        if (tid < 64) v += sred[1];
        if (tid < 128 && v >= n && v - h < n) { ctl[0] = tid; ctl[1] = n - (v - h); }
        __syncthreads();
        const int cutlvl = ctl[0];
        const int mm = ctl[1];
        // classify: keep above-cut; boundary tentatively kept + mini-list; clear below
#pragma unroll
        for (int g = 0; g < 4; ++g) {
            unsigned w = cw[g];
            unsigned outw = 0;
#pragma unroll
            for (int i = 0; i < 4; ++i) {
                unsigned code = (w >> (8 * i)) & 0xFFu;
                if (code) {
                    int lvl = (int)(code & 0x7Fu) - 1;
                    if (lvl > cutlvl) {
                        outw |= code << (8 * i);
                    } else if (lvl == cutlvl) {
                        outw |= code << (8 * i);
                        int idx = atomicAdd(&mcount, 1);
                        if (idx < MCAP) mlist[idx] = g * 1024 + tid * 4 + i;
                    }
                }
            }
            *(unsigned*)&enc[r][g * 1024 + tid * 4] = outw;
        }
        __syncthreads();
        int L = mcount; if (L > MCAP) L = MCAP;
#pragma unroll
        for (int g = 0; g < 4; ++g) {
#pragma unroll
            for (int i = 0; i < 4; ++i) {
                unsigned code = (cw[g] >> (8 * i)) & 0xFFu;
                if (code && (int)(code & 0x7Fu) - 1 == cutlvl) {
                    int mycol = g * 1024 + tid * 4 + i;
                    int rk = 0;
                    for (int t2 = 0; t2 < L; ++t2) rk += (mlist[t2] < mycol) ? 1 : 0;
                    if (rk >= mm) enc[r][mycol] = 0;    // tie-break by col asc
                }
            }
        }
        // own-thread writes only from here; write phase reads own entries -> no barrier
    }

    // ---------- write phase: reload W (cached), compose w2, full-line nt stores ----------
    int prn = 0, zrs = 0;
#pragma unroll
    for (int r = 0; r < R; ++r) {
        const int cp = (canp_bits >> r) & 1;
        const size_t rowoff = (size_t)(row0 + r) * N;
#pragma unroll
        for (int g = 0; g < 4; ++g) {
            const int j0 = g * 1024 + tid * 4;
            f32x4 w4 = *(const f32x4*)(W + rowoff + j0);     // L2/L3 reload
            unsigned cw = *(unsigned*)&enc[r][j0];
            f32x4 o;
#pragma unroll
            for (int i = 0; i < 4; ++i) {
                unsigned code = (cw >> (8 * i)) & 0xFFu;
                float w1 = code ? ((code & 0x80u) ? -INIT_STRENGTH : INIT_STRENGTH) : w4[i];
                int pr = (cp && fabsf(w1) < PRUNE_T) ? 1 : 0;
                float w2 = pr ? 0.f : w1;
                prn += pr;
                zrs += (fabsf(w2) < EPS) ? 1 : 0;
                o[i] = w2;
            }
            __builtin_nontemporal_store(o, (f32x4*)(out + rowoff + j0));
        }
    }

    // ---------- final counts ----------
#pragma unroll
    for (int off = 32; off > 0; off >>= 1) {
        prn += __shfl_down(prn, off, 64);
        zrs += __shfl_down(zrs, off, 64);
    }
    __syncthreads();
    if (lane == 0) { cred[wid][0] = prn; cred[wid][1] = zrs; }
    __syncthreads();
    if (tid == 0) {
        int tp = cred[0][0] + cred[1][0] + cred[2][0] + cred[3][0];
        int tz = cred[0][1] + cred[1][1] + cred[2][1] + cred[3][1];
        float* slot = acc + (blockIdx.x & (NSLOT - 1)) * 4;
        atomicAdd(slot + 0, (float)created_total);
        atomicAdd(slot + 1, (float)tp);
        atomicAdd(slot + 2, (float)tz);
    }
}

// ---------------- kernel 3: finalize scalars (one wave) ----------------
__global__ void final_kernel(const float* __restrict__ acc, float* __restrict__ out) {
    int t = threadIdx.x;   // 64 threads = NSLOT
    float c = acc[t * 4 + 0];
    float p = acc[t * 4 + 1];
    float z = acc[t * 4 + 2];
#pragma unroll
    for (int off = 32; off > 0; off >>= 1) {
        c += __shfl_down(c, off, 64);
        p += __shfl_down(p, off, 64);
        z += __shfl_down(z, off, 64);
    }
    if (t == 0) {
        out[NN + 0] = c;
        out[NN + 1] = p;
        out[NN + 2] = z * (1.0f / (float)NN);
    }
}

extern "C" void kernel_launch(void* const* d_in, const int* in_sizes, int n_in,
                              void* d_out, int out_size, void* d_ws, size_t ws_size,
                              hipStream_t stream) {
    const float* W   = (const float*)d_in[0];   // weight [4096,4096]
    const float* act = (const float*)d_in[1];   // activations [16,4096]
    float* out = (float*)d_out;                 // [w2 (N*N), created, pruned, sparsity]
    float* norm = (float*)d_ws;                 // [B][N] normalized activations
    float* acc = norm + (size_t)B * N;          // 64 slots x 4 float accumulators

    prep_kernel<<<N / 64, 64, 0, stream>>>(act, norm, acc);
    fused_kernel<<<N / R, 256, 0, stream>>>(W, norm, out, acc);
    final_kernel<<<1, 64, 0, stream>>>(acc, out);
}

// Round 7
// 225.026 us; speedup vs baseline: 1.7301x; 1.7301x over previous
//
#include <hip/hip_runtime.h>
#include <math.h>

#define N 4096
#define B 16
#define NN (N * N)
#define R 4                    // rows per block, grid = 1024 (proven R4 operating point)
#define MAX_SYN 100
#define MIN_SYN 10
#define CREATE_T 0.3f
#define PRUNE_T 0.01f
#define INIT_STRENGTH 0.01f
#define EPS 1e-10f
#define QSCALE 181.0f          // 127 levels over (0.3, ~1.0]
#define MCAP 128               // boundary-level mini-list cap
#define WKCAP 256              // weak (0<|W|<0.01) entry list cap (expected ~2/block)

typedef float f32x4 __attribute__((ext_vector_type(4)));

// ---------------- kernel 1: per-column normalization ----------------
// norm layout [B][N]; 64 blocks x 64 threads
__global__ void prep_kernel(const float* __restrict__ act,
                            float* __restrict__ norm) {
    const int tid = threadIdx.x;
    int j = blockIdx.x * 64 + tid;
    float a[B];
    float sum = 0.f;
#pragma unroll
    for (int b = 0; b < B; ++b) { a[b] = act[b * N + j]; sum += a[b]; }
    float mean = sum * (1.0f / B);
    float var = 0.f;
#pragma unroll
    for (int b = 0; b < B; ++b) { float c = a[b] - mean; var += c * c; }
    var *= (1.0f / (B - 1));   // ddof=1
    float sd = sqrtf(var);
    if (sd < 1e-8f) sd = 1e-8f;
    float inv = 1.0f / sd;
#pragma unroll
    for (int b = 0; b < B; ++b) norm[b * N + j] = (a[b] - mean) * inv;
}

// ---------------- kernel 2: fused corr + bulk prune-write + select + scatter ----------------
// enc code: 0 = nothing; else bit7 = sign(corr), bits0-6 = level+1 (level 0..126)
__global__ __launch_bounds__(256) void fused_kernel(const float* __restrict__ W,
                                                    const float* __restrict__ norm,
                                                    float* __restrict__ out,
                                                    float* __restrict__ slots) {
    __shared__ unsigned char enc[R][N];            // 16 KB
    __shared__ unsigned long long wklist[WKCAP];   // 2 KB: hi32=W bits, lo32=(r<<16)|col
    __shared__ int hist[128];
    __shared__ int cred[4][2 * R];
    __shared__ int sred[2];
    __shared__ int ctl[2];
    __shared__ int mlist[MCAP];
    __shared__ int mcount;
    __shared__ int wkcount;

    const int tid = threadIdx.x;
    const int lane = tid & 63;
    const int wid = tid >> 6;
    const int row0 = blockIdx.x * R;

    if (tid == 0) wkcount = 0;

    // wave-uniform row vectors
    float srow[R][B];
#pragma unroll
    for (int r = 0; r < R; ++r)
#pragma unroll
        for (int b = 0; b < B; ++b) srow[r][b] = norm[b * N + row0 + r];
    __syncthreads();   // wkcount=0 visible before pushes

    // ---------- pass A: corr + counts + encode + bulk prune-write ----------
    int cnt_nz[R], cnt_cand[R], cnt_str[R];
#pragma unroll
    for (int r = 0; r < R; ++r) { cnt_nz[r] = 0; cnt_cand[r] = 0; cnt_str[r] = 0; }

#pragma unroll
    for (int g = 0; g < 4; ++g) {
        const int j0 = g * 1024 + tid * 4;
        f32x4 w4[R];
#pragma unroll
        for (int r = 0; r < R; ++r)
            w4[r] = __builtin_nontemporal_load((const f32x4*)(W + (size_t)(row0 + r) * N + j0));
        float cc[R][4];
#pragma unroll
        for (int r = 0; r < R; ++r) { cc[r][0] = 0.f; cc[r][1] = 0.f; cc[r][2] = 0.f; cc[r][3] = 0.f; }
#pragma unroll
        for (int half = 0; half < 2; ++half) {     // 8 batch rows of norm in flight
            f32x4 nb[8];
#pragma unroll
            for (int b = 0; b < 8; ++b)
                nb[b] = *(const f32x4*)(norm + (half * 8 + b) * N + j0);
#pragma unroll
            for (int r = 0; r < R; ++r) {
#pragma unroll
                for (int b = 0; b < 8; ++b) {
                    float s = srow[r][half * 8 + b];
                    cc[r][0] = fmaf(s, nb[b][0], cc[r][0]);
                    cc[r][1] = fmaf(s, nb[b][1], cc[r][1]);
                    cc[r][2] = fmaf(s, nb[b][2], cc[r][2]);
                    cc[r][3] = fmaf(s, nb[b][3], cc[r][3]);
                }
            }
        }
#pragma unroll
        for (int r = 0; r < R; ++r) {
            unsigned pack = 0;
            f32x4 o;
#pragma unroll
            for (int i = 0; i < 4; ++i) {
                float c = cc[r][i] * 0.0625f;
                float w = w4[r][i];
                float aw = fabsf(w);
                float ac = fabsf(c);
                int nz = (aw > EPS) ? 1 : 0;
                int st = (aw >= PRUNE_T) ? 1 : 0;
                cnt_nz[r] += nz;
                cnt_str[r] += st;
                if ((ac > CREATE_T) && (aw < EPS)) {
                    cnt_cand[r] += 1;
                    int lvl = (int)((ac - CREATE_T) * QSCALE);
                    if (lvl > 126) lvl = 126;
                    unsigned code = (unsigned)(lvl + 1) | ((c < 0.f) ? 0x80u : 0u);
                    pack |= code << (8 * i);
                }
                // bulk value assumes can_prune (true for ~all rows); weak entries logged
                o[i] = st ? w : 0.f;
                if (nz && !st) {
                    int idx = atomicAdd(&wkcount, 1);
                    if (idx < WKCAP)
                        wklist[idx] = ((unsigned long long)__float_as_uint(w) << 32)
                                    | (unsigned)((r << 16) | (j0 + i));
                }
            }
            *(unsigned*)&enc[r][j0] = pack;
            *(f32x4*)(out + (size_t)(row0 + r) * N + j0) = o;   // regular cached store
        }
    }

    // ---------- reduce 2R packed counters ----------
    int vals[2 * R];
#pragma unroll
    for (int r = 0; r < R; ++r) {
        vals[r] = cnt_nz[r] | (cnt_str[r] << 16);
        vals[R + r] = cnt_cand[r];
    }
#pragma unroll
    for (int v = 0; v < 2 * R; ++v) {
        int x = vals[v];
#pragma unroll
        for (int off = 32; off > 0; off >>= 1) x += __shfl_down(x, off, 64);
        if (lane == 0) cred[wid][v] = x;
    }
    __syncthreads();   // also orders bulk out-stores before any later fix-up stores
    int tot[2 * R];
#pragma unroll
    for (int v = 0; v < 2 * R; ++v) tot[v] = cred[0][v] + cred[1][v] + cred[2][v] + cred[3][v];

    int nr[R];
    int canp_bits = 0;
    int created_total = 0, pruned_total = 0, zeros_total = 0;
#pragma unroll
    for (int r = 0; r < R; ++r) {
        int nz  = tot[r] & 0xFFFF;
        int str = tot[r] >> 16;
        int C = tot[R + r];
        int n = 0;
        if (nz < MAX_SYN) { int room = MAX_SYN - nz; n = C < room ? C : room; }
        nr[r] = n;
        created_total += n;
        int cp = ((str + n) > MIN_SYN) ? 1 : 0;    // strong(w1) = strong(W) + created
        canp_bits |= cp << r;
        // analytic counts: prune zeroes everything with |w1|<0.01 when canp
        pruned_total += cp ? (N - str - n) : 0;
        zeros_total  += cp ? (N - str - n) : (N - nz - n);
    }

    // ---------- per-row top-n selection on 7-bit levels ----------
#pragma unroll
    for (int r = 0; r < R; ++r) {
        const int n = nr[r];
        const int C = tot[R + r];
        if (n >= C) continue;           // all candidates created (uniform branch)
        if (n == 0) {                   // none created: clear row codes
#pragma unroll
            for (int g = 0; g < 4; ++g)
                *(unsigned*)&enc[r][g * 1024 + tid * 4] = 0u;
            continue;
        }
        __syncthreads();                // protect hist/mlist/ctl from previous row
        if (tid < 128) hist[tid] = 0;
        if (tid == 0) mcount = 0;
        __syncthreads();
        unsigned cw[4];
#pragma unroll
        for (int g = 0; g < 4; ++g) {
            cw[g] = *(unsigned*)&enc[r][g * 1024 + tid * 4];
#pragma unroll
            for (int i = 0; i < 4; ++i) {
                unsigned code = (cw[g] >> (8 * i)) & 0xFFu;
                if (code) atomicAdd(&hist[(code & 0x7Fu) - 1], 1);
            }
        }
        __syncthreads();
        // suffix sum over 127 bins (two waves, shfl)
        int h = 0, v = 0;
        if (tid < 128) {
            h = hist[tid];
            v = h;
#pragma unroll
            for (int off = 1; off < 64; off <<= 1) {
                int t = __shfl_down(v, off, 64);
                v += (lane + off < 64) ? t : 0;
            }
            if (lane == 0) sred[wid] = v;
        }
        __syncthreads();
        if (tid < 64) v += sred[1];
        if (tid < 128 && v >= n && v - h < n) { ctl[0] = tid; ctl[1] = n - (v - h); }
        __syncthreads();
        const int cutlvl = ctl[0];
        const int mm = ctl[1];
        // classify: keep above-cut; boundary tentatively kept + mini-list; clear below
#pragma unroll
        for (int g = 0; g < 4; ++g) {
            unsigned w = cw[g];
            unsigned outw = 0;
#pragma unroll
            for (int i = 0; i < 4; ++i) {
                unsigned code = (w >> (8 * i)) & 0xFFu;
                if (code) {
                    int lvl = (int)(code & 0x7Fu) - 1;
                    if (lvl > cutlvl) {
                        outw |= code << (8 * i);
                    } else if (lvl == cutlvl) {
                        outw |= code << (8 * i);
                        int idx = atomicAdd(&mcount, 1);
                        if (idx < MCAP) mlist[idx] = g * 1024 + tid * 4 + i;
                    }
                }
            }
            *(unsigned*)&enc[r][g * 1024 + tid * 4] = outw;
        }
        __syncthreads();
        int L = mcount; if (L > MCAP) L = MCAP;
#pragma unroll
        for (int g = 0; g < 4; ++g) {
#pragma unroll
            for (int i = 0; i < 4; ++i) {
                unsigned code = (cw[g] >> (8 * i)) & 0xFFu;
                if (code && (int)(code & 0x7Fu) - 1 == cutlvl) {
                    int mycol = g * 1024 + tid * 4 + i;
                    int rk = 0;
                    for (int t2 = 0; t2 < L; ++t2) rk += (mlist[t2] < mycol) ? 1 : 0;
                    if (rk >= mm) enc[r][mycol] = 0;    // tie-break by col asc
                }
            }
        }
    }

    // ---------- scatter created entries (own cols; same thread wrote the bulk line) ----------
#pragma unroll
    for (int r = 0; r < R; ++r) {
        const size_t rowoff = (size_t)(row0 + r) * N;
#pragma unroll
        for (int g = 0; g < 4; ++g) {
            const int j0 = g * 1024 + tid * 4;
            unsigned cw = *(unsigned*)&enc[r][j0];
            if (cw) {
#pragma unroll
                for (int i = 0; i < 4; ++i) {
                    unsigned code = (cw >> (8 * i)) & 0xFFu;
                    if (code)
                        out[rowoff + j0 + i] = (code & 0x80u) ? -INIT_STRENGTH : INIT_STRENGTH;
                }
            }
        }
    }

    // ---------- rare fix-up: restore weak entries on rows that can't prune ----------
    if (canp_bits != (1 << R) - 1) {
        int Lw = wkcount; if (Lw > WKCAP) Lw = WKCAP;
        for (int i = tid; i < Lw; i += 256) {
            unsigned long long e = wklist[i];
            unsigned rc = (unsigned)e;
            int r = (rc >> 16) & 0xFF;
            if (!((canp_bits >> r) & 1))
                out[(size_t)(row0 + r) * N + (rc & 0xFFFF)] = __uint_as_float((unsigned)(e >> 32));
        }
    }

    // ---------- per-block counts to dedicated slot (no atomics, no init needed) ----------
    if (tid == 0) {
        float* slot = slots + (size_t)blockIdx.x * 4;
        slot[0] = (float)created_total;
        slot[1] = (float)pruned_total;
        slot[2] = (float)zeros_total;
    }
}

// ---------------- kernel 3: finalize scalars (256 threads over 1024 slots) ----------------
__global__ void final_kernel(const float* __restrict__ slots, float* __restrict__ out) {
    __shared__ float red[4][3];
    const int tid = threadIdx.x;
    const int lane = tid & 63;
    const int wid = tid >> 6;
    float c = 0.f, p = 0.f, z = 0.f;
    for (int i = tid; i < N / R; i += 256) {
        c += slots[i * 4 + 0];
        p += slots[i * 4 + 1];
        z += slots[i * 4 + 2];
    }
#pragma unroll
    for (int off = 32; off > 0; off >>= 1) {
        c += __shfl_down(c, off, 64);
        p += __shfl_down(p, off, 64);
        z += __shfl_down(z, off, 64);
    }
    if (lane == 0) { red[wid][0] = c; red[wid][1] = p; red[wid][2] = z; }
    __syncthreads();
    if (tid == 0) {
        out[NN + 0] = red[0][0] + red[1][0] + red[2][0] + red[3][0];
        out[NN + 1] = red[0][1] + red[1][1] + red[2][1] + red[3][1];
        out[NN + 2] = (red[0][2] + red[1][2] + red[2][2] + red[3][2]) * (1.0f / (float)NN);
    }
}

extern "C" void kernel_launch(void* const* d_in, const int* in_sizes, int n_in,
                              void* d_out, int out_size, void* d_ws, size_t ws_size,
                              hipStream_t stream) {
    const float* W   = (const float*)d_in[0];   // weight [4096,4096]
    const float* act = (const float*)d_in[1];   // activations [16,4096]
    float* out = (float*)d_out;                 // [w2 (N*N), created, pruned, sparsity]
    float* norm = (float*)d_ws;                 // [B][N] normalized activations
    float* slots = norm + (size_t)B * N;        // 1024 blocks x 4 floats

    prep_kernel<<<N / 64, 64, 0, stream>>>(act, norm);
    fused_kernel<<<N / R, 256, 0, stream>>>(W, norm, out, slots);
    final_kernel<<<1, 256, 0, stream>>>(slots, out);
}